// Round 1
// baseline (595.548 us; speedup 1.0000x reference)
//
#include <hip/hip_runtime.h>
#include <hip/hip_bf16.h>
#include <math.h>

typedef unsigned short u16;
typedef __attribute__((ext_vector_type(8))) __bf16 bf16x8;
typedef __attribute__((ext_vector_type(4))) float floatx4;

#define SEQ   4096
#define BATCH 8
#define ROWS  32768   // BATCH*SEQ
#define C     512
#define NH    16
#define HD    32

__device__ inline u16 f2bf(float f) {
    union { float f; unsigned u; } v; v.f = f;
    unsigned r = (v.u + 0x7FFFu + ((v.u >> 16) & 1u)) >> 16;
    return (u16)r;
}
__device__ inline float bf2f(u16 h) {
    union { unsigned u; float f; } v; v.u = ((unsigned)h) << 16;
    return v.f;
}

// async global -> LDS, 16B per lane; lds ptr must be wave-uniform (HW adds lane*16)
__device__ inline void g2lds16(const u16* g, u16* l) {
    __builtin_amdgcn_global_load_lds((const __attribute__((address_space(1))) unsigned*)g,
                                     (__attribute__((address_space(3))) unsigned*)l, 16, 0, 0);
}

// ---------------- weight prep: fp32 (k,n) -> bf16 transposed (n,k), 64x64 LDS tiles ----------------
__global__ __launch_bounds__(256) void prep_weights(
    const float* __restrict__ Wq, const float* __restrict__ Wk,
    const float* __restrict__ Wv, const float* __restrict__ Wm,
    const float* __restrict__ W1, const float* __restrict__ W2,
    u16* __restrict__ Wqkvt, u16* __restrict__ Wmt,
    u16* __restrict__ W1t, u16* __restrict__ W2t)
{
    int blk = blockIdx.x;                 // 6 mats * 64 tiles
    int mat = blk >> 6;
    int tile = blk & 63;
    int k0 = (tile >> 3) * 64, n0 = (tile & 7) * 64;
    const float* src; u16* dst;
    switch (mat) {
        case 0: src = Wq; dst = Wqkvt;              break;
        case 1: src = Wk; dst = Wqkvt + 512*512;    break;
        case 2: src = Wv; dst = Wqkvt + 2*512*512;  break;
        case 3: src = Wm; dst = Wmt;                break;
        case 4: src = W1; dst = W1t;                break;
        default: src = W2; dst = W2t;               break;
    }
    __shared__ float ts[64][65];
    int t = threadIdx.x;
    #pragma unroll
    for (int i = 0; i < 16; i++) {
        int e = i * 256 + t;
        int kr = e >> 6, nc = e & 63;
        ts[kr][nc] = src[(size_t)(k0 + kr) * 512 + n0 + nc];   // coalesced 256B rows
    }
    __syncthreads();
    #pragma unroll
    for (int i = 0; i < 2; i++) {
        int e = i * 256 + t;                 // 512 chunks of 8
        int nr = e >> 3, kc0 = (e & 7) * 8;
        union { uint4 v; u16 u[8]; } o;
        #pragma unroll
        for (int q = 0; q < 8; q++) o.u[q] = f2bf(ts[kc0 + q][nr]);
        *(uint4*)(dst + (size_t)(n0 + nr) * 512 + k0 + kc0) = o.v;   // coalesced 16B stores
    }
}

// ---------------- layernorm: fp32 in -> bf16 out, one wave per row ----------------
__global__ __launch_bounds__(256) void ln_kernel(
    const float* __restrict__ in, const float* __restrict__ g,
    const float* __restrict__ b, u16* __restrict__ out)
{
    int row  = blockIdx.x * 4 + (threadIdx.x >> 6);
    int lane = threadIdx.x & 63;
    const float* p = in + (size_t)row * C + lane * 8;
    float4 v0 = *(const float4*)p;
    float4 v1 = *(const float4*)(p + 4);
    float s  = v0.x + v0.y + v0.z + v0.w + v1.x + v1.y + v1.z + v1.w;
    float s2 = v0.x*v0.x + v0.y*v0.y + v0.z*v0.z + v0.w*v0.w
             + v1.x*v1.x + v1.y*v1.y + v1.z*v1.z + v1.w*v1.w;
    #pragma unroll
    for (int off = 1; off < 64; off <<= 1) {
        s  += __shfl_xor(s, off);
        s2 += __shfl_xor(s2, off);
    }
    float mean = s * (1.f / C);
    float var  = s2 * (1.f / C) - mean * mean;
    float inv  = rsqrtf(var + 1e-6f);
    int c = lane * 8;
    float4 g0 = *(const float4*)(g + c), g1 = *(const float4*)(g + c + 4);
    float4 b0 = *(const float4*)(b + c), b1 = *(const float4*)(b + c + 4);
    union { uint4 v; u16 u[8]; } o;
    o.u[0] = f2bf((v0.x - mean) * inv * g0.x + b0.x);
    o.u[1] = f2bf((v0.y - mean) * inv * g0.y + b0.y);
    o.u[2] = f2bf((v0.z - mean) * inv * g0.z + b0.z);
    o.u[3] = f2bf((v0.w - mean) * inv * g0.w + b0.w);
    o.u[4] = f2bf((v1.x - mean) * inv * g1.x + b1.x);
    o.u[5] = f2bf((v1.y - mean) * inv * g1.y + b1.y);
    o.u[6] = f2bf((v1.z - mean) * inv * g1.z + b1.z);
    o.u[7] = f2bf((v1.w - mean) * inv * g1.w + b1.w);
    *(uint4*)(out + (size_t)row * C + c) = o.v;
}

// ---------------- bf16 MFMA GEMM, 256x256 tile, 8-phase counted-vmcnt schedule ----------------
// K is fixed at 512 for every call (qkv / Wm / W1 / W2).
// Geometry: BM=BN=256, BK=64, 8 waves (2M x 4N), 512 threads, 128 KiB LDS (2 slabs).
// Each slab = A[256][64] + B[256][64] bf16, rows XOR-rotated per (row&7) chunk (conflict-free,
// same scheme as the previous 128^2 kernel which measured 0 bank conflicts).
// Per iteration (2 K-tiles): 8 phases, each = {12 ds_read_b128 | stage 1 half-tile (2 gload_lds)
//   -> s_barrier -> lgkmcnt(0) -> setprio(1) 16 MFMA setprio(0) -> s_barrier}.
// Phase->quadrant: slab0:(0,0)(0,1)(1,1)(1,0) then slab1 same.  Half-tile free/stage schedule:
//   ph0: s1.A1<-t1   ph1: s1.B0<-t1   ph2: s0.A0<-t0+2  ph3: s0.B1<-t0+2  [vmcnt(4)]
//   ph4: s0.A1<-t0+2 ph5: s0.B0<-t0+2 ph6: s1.A0<-t1+2  ph7: s1.B1<-t1+2  [vmcnt(4)]
// Every stage targets a region whose last reader finished a barrier earlier; the vmcnt(4)
// sits BEFORE the mid-phase barrier so per-wave wait + barrier => all waves' loads landed.
// Loads are never drained to 0 in the main loop (T4); last iteration is peeled and drains.

#define STGA(S, H, KC)                                                          \
  do {                                                                          \
    const u16* _g = Ab + (size_t)((H) * 128) * 512 + (KC);                      \
    u16* _l = &lsA[S][(H) * 8192 + w * 1024];                                   \
    g2lds16(_g, _l);                                                            \
    g2lds16(_g + 8 * 512, _l + 512);                                            \
  } while (0)

#define STGB(S, H, KC)                                                          \
  do {                                                                          \
    const u16* _g = Bb + (size_t)((H) * 128) * 512 + (KC);                      \
    u16* _l = &lsB[S][(H) * 8192 + w * 1024];                                   \
    g2lds16(_g, _l);                                                            \
    g2lds16(_g + 8 * 512, _l + 512);                                            \
  } while (0)

#define PH(S, MH, NH, STG, VM)                                                  \
  do {                                                                          \
    bf16x8 af0[4], af1[4], bv0[2], bv1[2];                                      \
    const u16* As_ = &lsA[S][(MH) * 8192 + aoff];                               \
    const u16* Bs_ = &lsB[S][(NH) * 8192 + boff];                               \
    _Pragma("unroll") for (int ii = 0; ii < 4; ii++) {                          \
      af0[ii] = *(const bf16x8*)(As_ + ii * 1024 + ck0);                        \
      af1[ii] = *(const bf16x8*)(As_ + ii * 1024 + ck1);                        \
    }                                                                           \
    _Pragma("unroll") for (int jj = 0; jj < 2; jj++) {                          \
      bv0[jj] = *(const bf16x8*)(Bs_ + jj * 1024 + ck0);                        \
      bv1[jj] = *(const bf16x8*)(Bs_ + jj * 1024 + ck1);                        \
    }                                                                           \
    STG;                                                                        \
    __builtin_amdgcn_sched_barrier(0);                                          \
    if constexpr ((VM) == 4) asm volatile("s_waitcnt vmcnt(4)" ::: "memory");   \
    else if constexpr ((VM) == 0) asm volatile("s_waitcnt vmcnt(0)" ::: "memory"); \
    __builtin_amdgcn_s_barrier();                                               \
    asm volatile("s_waitcnt lgkmcnt(0)" ::: "memory");                          \
    __builtin_amdgcn_sched_barrier(0);                                          \
    __builtin_amdgcn_s_setprio(1);                                              \
    _Pragma("unroll") for (int ii = 0; ii < 4; ii++)                            \
      _Pragma("unroll") for (int jj = 0; jj < 2; jj++) {                        \
        acc[(MH)*4+ii][(NH)*2+jj] = __builtin_amdgcn_mfma_f32_16x16x32_bf16(    \
            af0[ii], bv0[jj], acc[(MH)*4+ii][(NH)*2+jj], 0, 0, 0);              \
        acc[(MH)*4+ii][(NH)*2+jj] = __builtin_amdgcn_mfma_f32_16x16x32_bf16(    \
            af1[ii], bv1[jj], acc[(MH)*4+ii][(NH)*2+jj], 0, 0, 0);              \
      }                                                                         \
    __builtin_amdgcn_s_setprio(0);                                              \
    __builtin_amdgcn_s_barrier();                                               \
  } while (0)

template <int EPI>
__global__ __launch_bounds__(512, 2) void gemm256(
    const u16* __restrict__ A, const u16* __restrict__ Bt,
    int ldc, int nx,
    u16* __restrict__ outb, float* __restrict__ outf,
    const float* __restrict__ bias, const float* __restrict__ resid)
{
    __shared__ u16 lsA[2][16384];   // [slab][256 rows x 64 cols]
    __shared__ u16 lsB[2][16384];
    const int t = threadIdx.x;
    const int w = t >> 6, l = t & 63, lr = l & 15, quad = l >> 4;
    const int wr = w >> 2, wc = w & 3;

    // grouped XCD swizzle: xcd g&7; within XCD sweep x-major over groups of 2 y-tiles
    // (A working set ~0.5MB + full B panel stay L2-resident -> A fetched ~once)
    const int g = blockIdx.x;
    const int xcd = g & 7;
    const int q = g >> 3;
    const int grp = q / (nx * 2), rem = q - grp * (nx * 2);
    const int tx = rem >> 1;
    const int ty = xcd * 16 + grp * 2 + (rem & 1);
    const int m0 = ty * 256, n0 = tx * 256;

    // staging addresses: wave w covers rows [w*16, w*16+16) of a 128-row half (2 loads)
    const int rh = w * 16 + (l >> 3);
    const int swz = (((l & 7) - (l >> 3)) & 7) * 8;   // rotated source chunk
    const u16* Ab = A  + (size_t)(m0 + rh) * 512 + swz;
    const u16* Bb = Bt + (size_t)(n0 + rh) * 512 + swz;

    // fragment read offsets (u16 units): row&7 == lr&7 -> physical chunk (mlog + lr)&7
    const int aoff = (wr * 64 + lr) * 64;
    const int boff = (wc * 32 + lr) * 64;
    const int ck0 = (((0 + quad + (lr & 7)) & 7) * 8);
    const int ck1 = (((4 + quad + (lr & 7)) & 7) * 8);

    floatx4 acc[8][4];
    #pragma unroll
    for (int i = 0; i < 8; i++)
        #pragma unroll
        for (int j = 0; j < 4; j++) { floatx4 z = {0.f, 0.f, 0.f, 0.f}; acc[i][j] = z; }

    // prologue: slab0 <- tile0 (all 4 halves), slab1 <- tile1 {A-h0, B-h1}
    STGA(0, 0, 0); STGA(0, 1, 0); STGB(0, 0, 0); STGB(0, 1, 0);
    STGA(1, 0, 64); STGB(1, 1, 64);
    asm volatile("s_waitcnt vmcnt(4)" ::: "memory");   // slab0's 8 landed
    __builtin_amdgcn_s_barrier();

    int kk = 0;
    for (int it = 0; it < 3; ++it, kk += 128) {        // K=512 -> 4 iters, last peeled
        PH(0, 0, 0, STGA(1, 1, kk + 64),  -1);
        PH(0, 0, 1, STGB(1, 0, kk + 64),  -1);
        PH(0, 1, 1, STGA(0, 0, kk + 128), -1);
        PH(0, 1, 0, STGB(0, 1, kk + 128),  4);
        PH(1, 0, 0, STGA(0, 1, kk + 128), -1);
        PH(1, 0, 1, STGB(0, 0, kk + 128), -1);
        PH(1, 1, 1, STGA(1, 0, kk + 192), -1);
        PH(1, 1, 0, STGB(1, 1, kk + 192),  4);
    }
    // last iteration: finish staging tile 7 halves, no further prefetch, drain once
    PH(0, 0, 0, STGA(1, 1, kk + 64), -1);
    PH(0, 0, 1, STGB(1, 0, kk + 64), -1);
    PH(0, 1, 1, (void)0, -1);
    PH(0, 1, 0, (void)0,  0);
    PH(1, 0, 0, (void)0, -1);
    PH(1, 0, 1, (void)0, -1);
    PH(1, 1, 1, (void)0, -1);
    PH(1, 1, 0, (void)0, -1);

    // epilogue
    #pragma unroll
    for (int i = 0; i < 8; i++) {
        #pragma unroll
        for (int j = 0; j < 4; j++) {
            #pragma unroll
            for (int r = 0; r < 4; r++) {
                int row = m0 + (i >> 2) * 128 + wr * 64 + (i & 3) * 16 + quad * 4 + r;
                int col = n0 + (j >> 1) * 128 + wc * 32 + (j & 1) * 16 + lr;
                float v = acc[i][j][r];
                size_t idx = (size_t)row * ldc + col;
                if constexpr (EPI == 0) {
                    if (col < 1024) v = v > 0.f ? v + 1.f : __expf(v);
                    else            v *= (1.0f / SEQ);
                    outb[idx] = f2bf(v);
                } else if constexpr (EPI == 1) {
                    outf[idx] = resid[idx] + v;
                } else if constexpr (EPI == 2) {
                    v += bias[col];
                    v = 0.5f * v * (1.f + erff(v * 0.70710678118f));
                    outb[idx] = f2bf(v);
                } else {
                    outf[idx] = outf[idx] + v + bias[col];
                }
            }
        }
    }
}

// ---------------- KV partials via MFMA: per-wave private LDS tiles, no atomics ----------------
__global__ __launch_bounds__(256) void kv_reduce(
    const u16* __restrict__ qkv, float* __restrict__ Pkv, float* __restrict__ PKsum)
{
    const int bh = blockIdx.x;            // 0..127
    const int b = bh >> 4, h = bh & 15;
    const int chunk = blockIdx.y;         // 0..7
    const int t = threadIdx.x;
    const int w = t >> 6, l = t & 63, lr = l & 15, quad = l >> 4;
    __shared__ u16 lds[4 * 2 * 2048];     // [wave][buf][K 1024 | V 1024] = 32 KB

    const int sbase = chunk * 512 + w * 128;
    const u16* qbase = qkv + (size_t)b * SEQ * 1536 + 512 + h * HD;  // K part; V = +512

    const int sl0 = l >> 2;               // rows 0..15 (instr 0)
    const int sl1 = 16 + sl0;             // rows 16..31 (instr 1)
    const int cl  = l & 3;
    const int cg0 = (cl + (sl0 >> 3)) & 3;
    const int cg1 = (cl + (sl1 >> 3)) & 3;
    const int gof0 = sl0 * 1536 + cg0 * 8;
    const int gof1 = sl1 * 1536 + cg1 * 8;

    u16* myl = lds + w * 4096;

    const int offA0 = quad * 256 + ((((lr >> 3) + 0) - quad) & 3) * 8 + (lr & 7);  // d 0..15
    const int offA1 = quad * 256 + ((((lr >> 3) + 2) - quad) & 3) * 8 + (lr & 7);  // d 16..31

    floatx4 a00 = {0,0,0,0}, a01 = {0,0,0,0}, a10 = {0,0,0,0}, a11 = {0,0,0,0};
    float ks0 = 0.f, ks1 = 0.f;

    {
        const u16* gK = qbase + (size_t)sbase * 1536;
        g2lds16(gK + gof0,       myl);
        g2lds16(gK + gof1,       myl + 512);
        g2lds16(gK + 512 + gof0, myl + 1024);
        g2lds16(gK + 512 + gof1, myl + 1536);
    }
    #pragma unroll
    for (int st = 0; st < 4; st++) {
        if (st < 3) {                      // prefetch next buf before the drain
            const u16* gK = qbase + (size_t)(sbase + (st + 1) * 32) * 1536;
            u16* nl = myl + ((st + 1) & 1) * 2048;
            g2lds16(gK + gof0,       nl);
            g2lds16(gK + gof1,       nl + 512);
            g2lds16(gK + 512 + gof0, nl + 1024);
            g2lds16(gK + 512 + gof1, nl + 1536);
        }
        __syncthreads();                   // vmcnt(0) drain, compiler-safe fence
        const u16* lK = myl + (st & 1) * 2048;
        const u16* lV = lK + 1024;
        union { bf16x8 v; u16 u[8]; } fa0, fa1, fb0, fb1;
        #pragma unroll
        for (int j = 0; j < 8; j++) {
            fa0.u[j] = lK[offA0 + j * 32];
            fa1.u[j] = lK[offA1 + j * 32];
            fb0.u[j] = lV[offA0 + j * 32];
            fb1.u[j] = lV[offA1 + j * 32];
        }
        #pragma unroll
        for (int j = 0; j < 8; j++) { ks0 += bf2f(fa0.u[j]); ks1 += bf2f(fa1.u[j]); }
        a00 = __builtin_amdgcn_mfma_f32_16x16x32_bf16(fa0.v, fb0.v, a00, 0, 0, 0);
        a01 = __builtin_amdgcn_mfma_f32_16x16x32_bf16(fa0.v, fb1.v, a01, 0, 0, 0);
        a10 = __builtin_amdgcn_mfma_f32_16x16x32_bf16(fa1.v, fb0.v, a10, 0, 0, 0);
        a11 = __builtin_amdgcn_mfma_f32_16x16x32_bf16(fa1.v, fb1.v, a11, 0, 0, 0);
    }

    const int p = bh * 32 + chunk * 4 + w;
    float* dst = Pkv + (size_t)p * 1024;
    floatx4 accs[2][2] = {{a00, a01}, {a10, a11}};
    #pragma unroll
    for (int i = 0; i < 2; i++)
        #pragma unroll
        for (int j = 0; j < 2; j++)
            #pragma unroll
            for (int r = 0; r < 4; r++)
                dst[(i * 16 + quad * 4 + r) * 32 + j * 16 + lr] = accs[i][j][r];

    float k0 = ks0 + __shfl_xor(ks0, 16); k0 += __shfl_xor(k0, 32);
    float k1 = ks1 + __shfl_xor(ks1, 16); k1 += __shfl_xor(k1, 32);
    if (quad == 0) {
        PKsum[p * 32 + lr]      = k0;
        PKsum[p * 32 + 16 + lr] = k1;
    }
}

// ---------------- final reduce: KV[bh][1024] = sum of 32 partials; Ksum likewise ----------------
__global__ __launch_bounds__(256) void kv_final(
    const float* __restrict__ Pkv, const float* __restrict__ PKsum,
    float* __restrict__ KV, float* __restrict__ Ksum)
{
    const int bh = blockIdx.x;
    const int t = threadIdx.x;
    float a0 = 0.f, a1 = 0.f, a2 = 0.f, a3 = 0.f;
    for (int p = 0; p < 32; p++) {
        const float* src = Pkv + ((size_t)bh * 32 + p) * 1024;
        a0 += src[t];
        a1 += src[t + 256];
        a2 += src[t + 512];
        a3 += src[t + 768];
    }
    float* dst = KV + (size_t)bh * 1024;
    dst[t] = a0; dst[t + 256] = a1; dst[t + 512] = a2; dst[t + 768] = a3;
    if (t < 32) {
        float s = 0.f;
        for (int p = 0; p < 32; p++) s += PKsum[(bh * 32 + p) * 32 + t];
        Ksum[bh * 32 + t] = s;
    }
}

// ---------------- msg = (Q . KV) * SEQ / (Q . Ksum + eps) ----------------
__global__ __launch_bounds__(256) void msg_kernel(
    const u16* __restrict__ qkv, const float* __restrict__ KV,
    const float* __restrict__ Ksum, u16* __restrict__ msg)
{
    int blk = blockIdx.x;           // 1024 blocks
    int b = blk >> 7;
    int r0 = (blk & 127) * 32;
    int t = threadIdx.x;
    int h = t >> 4;
    int vd = (t & 15) * 2;
    float kv0[32], kv1[32], ksr[32];
    const float* kvh = KV + ((size_t)b * 16 + h) * 1024;
    const float* ksh = Ksum + (b * 16 + h) * 32;
    #pragma unroll
    for (int d = 0; d < 32; d++) {
        kv0[d] = kvh[d * 32 + vd];
        kv1[d] = kvh[d * 32 + vd + 1];
        ksr[d] = ksh[d];
    }
    __shared__ u16 Qs[4 * 512];
    const int srr = t >> 6;
    const int scc = (t & 63) * 8;
    for (int rg = 0; rg < 32; rg += 4) {
        size_t row = (size_t)b * SEQ + r0 + rg;
        uint4 qv = *(const uint4*)(qkv + (row + srr) * 1536 + scc);
        __syncthreads();
        *(uint4*)(Qs + srr * 512 + scc) = qv;
        __syncthreads();
        #pragma unroll
        for (int r2 = 0; r2 < 4; r2++) {
            const u16* qp = Qs + r2 * 512 + h * HD;
            float q[32];
            #pragma unroll
            for (int i0 = 0; i0 < 32; i0 += 8) {
                union { uint4 v; u16 u[8]; } uu;
                uu.v = *(const uint4*)(qp + i0);
                #pragma unroll
                for (int jq = 0; jq < 8; jq++) q[i0 + jq] = bf2f(uu.u[jq]);
            }
            float zdot = 0.f, m0 = 0.f, m1 = 0.f;
            #pragma unroll
            for (int d = 0; d < 32; d++) {
                float qd = q[d];
                zdot += qd * ksr[d];
                m0   += qd * kv0[d];
                m1   += qd * kv1[d];
            }
            float z = (float)SEQ / (zdot + 1e-6f);
            unsigned pack = (unsigned)f2bf(m0 * z) | ((unsigned)f2bf(m1 * z) << 16);
            *(unsigned*)(msg + (row + r2) * C + h * HD + vd) = pack;
        }
    }
}

extern "C" void kernel_launch(void* const* d_in, const int* in_sizes, int n_in,
                              void* d_out, int out_size, void* d_ws, size_t ws_size,
                              hipStream_t stream) {
    const float* x     = (const float*)d_in[0];
    const float* Wq    = (const float*)d_in[1];
    const float* Wk    = (const float*)d_in[2];
    const float* Wv    = (const float*)d_in[3];
    const float* Wm    = (const float*)d_in[4];
    const float* W1    = (const float*)d_in[5];
    const float* b1    = (const float*)d_in[6];
    const float* W2    = (const float*)d_in[7];
    const float* b2    = (const float*)d_in[8];
    const float* g_att = (const float*)d_in[9];
    const float* b_att = (const float*)d_in[10];
    const float* g_ffn = (const float*)d_in[11];
    const float* b_ffn = (const float*)d_in[12];
    float* out = (float*)d_out;

    // Workspace map (live ranges disjoint in time)
    char* ws = (char*)d_ws;
    u16*   Wqkvt = (u16*)(ws);                    // 1.5 MB
    u16*   Wmt   = (u16*)(ws + 0x180000);         // 0.5 MB
    u16*   W1t   = (u16*)(ws + 0x200000);         // 0.5 MB
    u16*   W2t   = (u16*)(ws + 0x280000);         // 0.5 MB
    float* KV    = (float*)(ws + 0x300000);       // 512 KB
    float* Ksum  = (float*)(ws + 0x380000);       // 16 KB
    u16*   hb    = (u16*)(ws + 0x400000);         // 32 MB (LN1 out; reused as msg)
    float* Pkv   = (float*)(ws + 0x400000);       // 16 MB, aliases hb (hb dead in step 4)
    float* PKsum = (float*)(ws + 0x1400000);      // 512 KB
    u16*   qkv   = (u16*)(ws + 0x2400000);        // 96 MB
    u16*   h2    = qkv;                           // 32 MB (qkv dead after step 5)
    u16*   f1    = (u16*)(ws + 0x4400000);        // 32 MB (in qkv tail, dead by step 8)

    // 1. weights -> bf16 transposed
    prep_weights<<<6 * 64, 256, 0, stream>>>(Wq, Wk, Wv, Wm, W1, W2,
                                             Wqkvt, Wmt, W1t, W2t);
    // 2. LN1
    ln_kernel<<<ROWS / 4, 256, 0, stream>>>(x, g_att, b_att, hb);
    // 3. qkv = h @ [Wq|Wk|Wv] with feature-map epilogue  (256^2 8-phase)
    gemm256<0><<<768, 512, 0, stream>>>(hb, Wqkvt, 1536, 6,
                                        qkv, nullptr, nullptr, nullptr);
    // 4. KV/Ksum: MFMA partials + final reduce (no atomics, no memset)
    kv_reduce<<<dim3(128, 8), 256, 0, stream>>>(qkv, Pkv, PKsum);
    kv_final<<<128, 256, 0, stream>>>(Pkv, PKsum, KV, Ksum);
    // 5. msg (overwrites hb region - Pkv already consumed)
    msg_kernel<<<1024, 256, 0, stream>>>(qkv, KV, Ksum, hb);
    // 6. x2 = x + msg @ Wm   (x2 lives in d_out)
    gemm256<1><<<256, 512, 0, stream>>>(hb, Wmt, 512, 2,
                                        nullptr, out, nullptr, x);
    // 7. LN2
    ln_kernel<<<ROWS / 4, 256, 0, stream>>>(out, g_ffn, b_ffn, h2);
    // 8. f1 = gelu(h2 @ W1 + b1)
    gemm256<2><<<256, 512, 0, stream>>>(h2, W1t, 512, 2,
                                        f1, nullptr, b1, nullptr);
    // 9. out = x2 + f1 @ W2 + b2   (in place on d_out)
    gemm256<3><<<256, 512, 0, stream>>>(f1, W2t, 512, 2,
                                        nullptr, out, b2, nullptr);
}

// Round 2
// 421.291 us; speedup vs baseline: 1.4136x; 1.4136x over previous
//
#include <hip/hip_runtime.h>
#include <hip/hip_bf16.h>
#include <math.h>

typedef unsigned short u16;
typedef __attribute__((ext_vector_type(8))) __bf16 bf16x8;
typedef __attribute__((ext_vector_type(4))) float floatx4;

#define SEQ   4096
#define BATCH 8
#define ROWS  32768   // BATCH*SEQ
#define C     512
#define NH    16
#define HD    32

__device__ inline u16 f2bf(float f) {
    union { float f; unsigned u; } v; v.f = f;
    unsigned r = (v.u + 0x7FFFu + ((v.u >> 16) & 1u)) >> 16;
    return (u16)r;
}
__device__ inline float bf2f(u16 h) {
    union { unsigned u; float f; } v; v.u = ((unsigned)h) << 16;
    return v.f;
}

// async global -> LDS, 16B per lane; lds ptr must be wave-uniform (HW adds lane*16)
__device__ inline void g2lds16(const u16* g, u16* l) {
    __builtin_amdgcn_global_load_lds((const __attribute__((address_space(1))) unsigned*)g,
                                     (__attribute__((address_space(3))) unsigned*)l, 16, 0, 0);
}

// ---------------- weight prep: fp32 (k,n) -> bf16 transposed (n,k), 64x64 LDS tiles ----------------
__global__ __launch_bounds__(256) void prep_weights(
    const float* __restrict__ Wq, const float* __restrict__ Wk,
    const float* __restrict__ Wv, const float* __restrict__ Wm,
    const float* __restrict__ W1, const float* __restrict__ W2,
    u16* __restrict__ Wqkvt, u16* __restrict__ Wmt,
    u16* __restrict__ W1t, u16* __restrict__ W2t)
{
    int blk = blockIdx.x;                 // 6 mats * 64 tiles
    int mat = blk >> 6;
    int tile = blk & 63;
    int k0 = (tile >> 3) * 64, n0 = (tile & 7) * 64;
    const float* src; u16* dst;
    switch (mat) {
        case 0: src = Wq; dst = Wqkvt;              break;
        case 1: src = Wk; dst = Wqkvt + 512*512;    break;
        case 2: src = Wv; dst = Wqkvt + 2*512*512;  break;
        case 3: src = Wm; dst = Wmt;                break;
        case 4: src = W1; dst = W1t;                break;
        default: src = W2; dst = W2t;               break;
    }
    __shared__ float ts[64][65];
    int t = threadIdx.x;
    #pragma unroll
    for (int i = 0; i < 16; i++) {
        int e = i * 256 + t;
        int kr = e >> 6, nc = e & 63;
        ts[kr][nc] = src[(size_t)(k0 + kr) * 512 + n0 + nc];   // coalesced 256B rows
    }
    __syncthreads();
    #pragma unroll
    for (int i = 0; i < 2; i++) {
        int e = i * 256 + t;                 // 512 chunks of 8
        int nr = e >> 3, kc0 = (e & 7) * 8;
        union { uint4 v; u16 u[8]; } o;
        #pragma unroll
        for (int q = 0; q < 8; q++) o.u[q] = f2bf(ts[kc0 + q][nr]);
        *(uint4*)(dst + (size_t)(n0 + nr) * 512 + k0 + kc0) = o.v;   // coalesced 16B stores
    }
}

// ---------------- layernorm: fp32 in -> bf16 out, one wave per row ----------------
__global__ __launch_bounds__(256) void ln_kernel(
    const float* __restrict__ in, const float* __restrict__ g,
    const float* __restrict__ b, u16* __restrict__ out)
{
    int row  = blockIdx.x * 4 + (threadIdx.x >> 6);
    int lane = threadIdx.x & 63;
    const float* p = in + (size_t)row * C + lane * 8;
    float4 v0 = *(const float4*)p;
    float4 v1 = *(const float4*)(p + 4);
    float s  = v0.x + v0.y + v0.z + v0.w + v1.x + v1.y + v1.z + v1.w;
    float s2 = v0.x*v0.x + v0.y*v0.y + v0.z*v0.z + v0.w*v0.w
             + v1.x*v1.x + v1.y*v1.y + v1.z*v1.z + v1.w*v1.w;
    #pragma unroll
    for (int off = 1; off < 64; off <<= 1) {
        s  += __shfl_xor(s, off);
        s2 += __shfl_xor(s2, off);
    }
    float mean = s * (1.f / C);
    float var  = s2 * (1.f / C) - mean * mean;
    float inv  = rsqrtf(var + 1e-6f);
    int c = lane * 8;
    float4 g0 = *(const float4*)(g + c), g1 = *(const float4*)(g + c + 4);
    float4 b0 = *(const float4*)(b + c), b1 = *(const float4*)(b + c + 4);
    union { uint4 v; u16 u[8]; } o;
    o.u[0] = f2bf((v0.x - mean) * inv * g0.x + b0.x);
    o.u[1] = f2bf((v0.y - mean) * inv * g0.y + b0.y);
    o.u[2] = f2bf((v0.z - mean) * inv * g0.z + b0.z);
    o.u[3] = f2bf((v0.w - mean) * inv * g0.w + b0.w);
    o.u[4] = f2bf((v1.x - mean) * inv * g1.x + b1.x);
    o.u[5] = f2bf((v1.y - mean) * inv * g1.y + b1.y);
    o.u[6] = f2bf((v1.z - mean) * inv * g1.z + b1.z);
    o.u[7] = f2bf((v1.w - mean) * inv * g1.w + b1.w);
    *(uint4*)(out + (size_t)row * C + c) = o.v;
}

// ---------------- bf16 MFMA GEMM, 256x256 tile, 8-phase counted-vmcnt schedule ----------------
// K fixed at 512. BM=BN=256, BK=64, 8 waves (2M x 4N), 512 threads, 128 KiB LDS.
// KEY FIX vs Round 1: the double-buffered LDS is split into EIGHT DISTINCT __shared__ arrays
// (one per slab-half). Round 1 used one lsA[2][16384] object; LLVM's waitcnt pass could not
// prove the per-phase ds_reads don't alias in-flight global_load_lds writes to the same object
// and inserted a conservative vmcnt(0) drain before every phase's reads -> full HBM latency
// exposed serially per phase (MfmaUtil 4.5%). Distinct objects -> NoAlias -> counted vmcnt
// survives and loads span phases (T3+T4).
// Per iteration (2 K-tiles): 8 phases; reads per phase follow m201's 12/4/8/4 pattern
// (A-frags retained 2 phases, B-h0 re-read at phase d; peak frag liveness 12 regs).
// Stage schedule per iter (2 loads each):
//   ph0: A1h1<-k+64   ph1: B1h0<-k+64   ph2: A0h0<-k+128  ph3: B0h1<-k+128 [vmcnt(4)]
//   ph4: A0h1<-k+128  ph5: B0h0<-k+128  ph6: A1h0<-k+192  ph7: B1h1<-k+192 [vmcnt(4)]
// vmcnt(4) before the mid-phase barrier => all waves' slab loads landed after the barrier.
// Never drains to 0 in the main loop; tail peeled with one vmcnt(0).

#define STG2(ARR, GBASE, KC)                                                    \
  do {                                                                          \
    const u16* _g = (GBASE) + (KC);                                             \
    u16* _l = (ARR) + w * 1024;                                                 \
    g2lds16(_g, _l);                                                            \
    g2lds16(_g + 8 * 512, _l + 512);                                            \
  } while (0)

#define RDA(ARR)                                                                \
  do {                                                                          \
    const u16* As_ = (ARR) + aoff;                                              \
    _Pragma("unroll") for (int ii = 0; ii < 4; ii++) {                          \
      af0[ii] = *(const bf16x8*)(As_ + ii * 1024 + ck0);                        \
      af1[ii] = *(const bf16x8*)(As_ + ii * 1024 + ck1);                        \
    }                                                                           \
  } while (0)

#define RDB(ARR)                                                                \
  do {                                                                          \
    const u16* Bs_ = (ARR) + boff;                                              \
    _Pragma("unroll") for (int jj = 0; jj < 2; jj++) {                          \
      bv0[jj] = *(const bf16x8*)(Bs_ + jj * 1024 + ck0);                        \
      bv1[jj] = *(const bf16x8*)(Bs_ + jj * 1024 + ck1);                        \
    }                                                                           \
  } while (0)

#define PHX(MH, NHI, STG, VM)                                                   \
  do {                                                                          \
    STG;                                                                        \
    __builtin_amdgcn_sched_barrier(0);                                          \
    if constexpr ((VM) == 4) asm volatile("s_waitcnt vmcnt(4)" ::: "memory");   \
    else if constexpr ((VM) == 0) asm volatile("s_waitcnt vmcnt(0)" ::: "memory"); \
    __builtin_amdgcn_s_barrier();                                               \
    asm volatile("s_waitcnt lgkmcnt(0)" ::: "memory");                          \
    __builtin_amdgcn_sched_barrier(0);                                          \
    __builtin_amdgcn_s_setprio(1);                                              \
    _Pragma("unroll") for (int ii = 0; ii < 4; ii++)                            \
      _Pragma("unroll") for (int jj = 0; jj < 2; jj++) {                        \
        acc[(MH)*4+ii][(NHI)*2+jj] = __builtin_amdgcn_mfma_f32_16x16x32_bf16(   \
            af0[ii], bv0[jj], acc[(MH)*4+ii][(NHI)*2+jj], 0, 0, 0);             \
        acc[(MH)*4+ii][(NHI)*2+jj] = __builtin_amdgcn_mfma_f32_16x16x32_bf16(   \
            af1[ii], bv1[jj], acc[(MH)*4+ii][(NHI)*2+jj], 0, 0, 0);             \
      }                                                                         \
    __builtin_amdgcn_s_setprio(0);                                              \
    __builtin_amdgcn_s_barrier();                                               \
    __builtin_amdgcn_sched_barrier(0);                                          \
  } while (0)

template <int EPI>
__global__ __launch_bounds__(512, 2) void gemm256(
    const u16* __restrict__ A, const u16* __restrict__ Bt,
    int ldc, int nx,
    u16* __restrict__ outb, float* __restrict__ outf,
    const float* __restrict__ bias, const float* __restrict__ resid)
{
    // 8 distinct LDS objects: [slab][half], each 128 rows x 64 cols bf16 = 16 KB
    __shared__ u16 A0h0[8192], A0h1[8192], A1h0[8192], A1h1[8192];
    __shared__ u16 B0h0[8192], B0h1[8192], B1h0[8192], B1h1[8192];

    const int t = threadIdx.x;
    const int w = t >> 6, l = t & 63, lr = l & 15, quad = l >> 4;
    const int wr = w >> 2, wc = w & 3;

    // grouped XCD swizzle: xcd g&7; within XCD sweep x-major over groups of 2 y-tiles
    const int g = blockIdx.x;
    const int xcd = g & 7;
    const int q = g >> 3;
    const int grp = q / (nx * 2), rem = q - grp * (nx * 2);
    const int tx = rem >> 1;
    const int ty = xcd * 16 + grp * 2 + (rem & 1);
    const int m0 = ty * 256, n0 = tx * 256;

    // staging addresses: wave w covers rows [w*16, w*16+16) of a 128-row half (2 loads)
    const int rh = w * 16 + (l >> 3);
    const int swz = (((l & 7) - (l >> 3)) & 7) * 8;   // rotated source chunk
    const u16* Ab0 = A  + (size_t)(m0 + rh) * 512 + swz;
    const u16* Bb0 = Bt + (size_t)(n0 + rh) * 512 + swz;
    const u16* Ab1 = Ab0 + (size_t)128 * 512;
    const u16* Bb1 = Bb0 + (size_t)128 * 512;

    // fragment read offsets (u16 units); row&7 == lr&7 -> physical chunk (m + lr)&7
    const int aoff = (wr * 64 + lr) * 64;
    const int boff = (wc * 32 + lr) * 64;
    const int ck0 = (((0 + quad + (lr & 7)) & 7) * 8);
    const int ck1 = (((4 + quad + (lr & 7)) & 7) * 8);

    floatx4 acc[8][4];
    #pragma unroll
    for (int i = 0; i < 8; i++)
        #pragma unroll
        for (int j = 0; j < 4; j++) { floatx4 z = {0.f, 0.f, 0.f, 0.f}; acc[i][j] = z; }

    bf16x8 af0[4], af1[4], bv0[2], bv1[2];

    // prologue: slab0 <- tile0 (all 4 halves), slab1 <- tile1 {A-h0, B-h1}
    STG2(A0h0, Ab0, 0); STG2(A0h1, Ab1, 0); STG2(B0h0, Bb0, 0); STG2(B0h1, Bb1, 0);
    STG2(A1h0, Ab0, 64); STG2(B1h1, Bb1, 64);
    asm volatile("s_waitcnt vmcnt(4)" ::: "memory");   // slab0's 8 landed
    __builtin_amdgcn_s_barrier();
    __builtin_amdgcn_sched_barrier(0);

    int kk = 0;
    for (int it = 0; it < 3; ++it, kk += 128) {        // K=512 -> 4 iters, last peeled
        RDA(A0h0); RDB(B0h0); PHX(0, 0, STG2(A1h1, Ab1, kk + 64),  -1);
        RDB(B0h1);            PHX(0, 1, STG2(B1h0, Bb0, kk + 64),  -1);
        RDA(A0h1);            PHX(1, 1, STG2(A0h0, Ab0, kk + 128), -1);
        RDB(B0h0);            PHX(1, 0, STG2(B0h1, Bb1, kk + 128),  4);
        RDA(A1h0); RDB(B1h0); PHX(0, 0, STG2(A0h1, Ab1, kk + 128), -1);
        RDB(B1h1);            PHX(0, 1, STG2(B0h0, Bb0, kk + 128), -1);
        RDA(A1h1);            PHX(1, 1, STG2(A1h0, Ab0, kk + 192), -1);
        RDB(B1h0);            PHX(1, 0, STG2(B1h1, Bb1, kk + 192),  4);
    }
    // tail (kk=384): slab0 holds 384; finish staging 448 into slab1; one vmcnt(0)
    RDA(A0h0); RDB(B0h0); PHX(0, 0, STG2(A1h1, Ab1, 448), -1);
    RDB(B0h1);            PHX(0, 1, STG2(B1h0, Bb0, 448), -1);
    RDA(A0h1);            PHX(1, 1, (void)0, -1);
    RDB(B0h0);            PHX(1, 0, (void)0,  0);
    RDA(A1h0); RDB(B1h0); PHX(0, 0, (void)0, -1);
    RDB(B1h1);            PHX(0, 1, (void)0, -1);
    RDA(A1h1);            PHX(1, 1, (void)0, -1);
    RDB(B1h0);            PHX(1, 0, (void)0, -1);

    // epilogue
    #pragma unroll
    for (int i = 0; i < 8; i++) {
        #pragma unroll
        for (int j = 0; j < 4; j++) {
            #pragma unroll
            for (int r = 0; r < 4; r++) {
                int row = m0 + (i >> 2) * 128 + wr * 64 + (i & 3) * 16 + quad * 4 + r;
                int col = n0 + (j >> 1) * 128 + wc * 32 + (j & 1) * 16 + lr;
                float v = acc[i][j][r];
                size_t idx = (size_t)row * ldc + col;
                if constexpr (EPI == 0) {
                    if (col < 1024) v = v > 0.f ? v + 1.f : __expf(v);
                    else            v *= (1.0f / SEQ);
                    outb[idx] = f2bf(v);
                } else if constexpr (EPI == 1) {
                    outf[idx] = resid[idx] + v;
                } else if constexpr (EPI == 2) {
                    v += bias[col];
                    v = 0.5f * v * (1.f + erff(v * 0.70710678118f));
                    outb[idx] = f2bf(v);
                } else {
                    outf[idx] = outf[idx] + v + bias[col];
                }
            }
        }
    }
}

// ---------------- KV partials via MFMA: per-wave private LDS tiles, no atomics ----------------
__global__ __launch_bounds__(256) void kv_reduce(
    const u16* __restrict__ qkv, float* __restrict__ Pkv, float* __restrict__ PKsum)
{
    const int bh = blockIdx.x;            // 0..127
    const int b = bh >> 4, h = bh & 15;
    const int chunk = blockIdx.y;         // 0..7
    const int t = threadIdx.x;
    const int w = t >> 6, l = t & 63, lr = l & 15, quad = l >> 4;
    __shared__ u16 lds[4 * 2 * 2048];     // [wave][buf][K 1024 | V 1024] = 32 KB

    const int sbase = chunk * 512 + w * 128;
    const u16* qbase = qkv + (size_t)b * SEQ * 1536 + 512 + h * HD;  // K part; V = +512

    const int sl0 = l >> 2;               // rows 0..15 (instr 0)
    const int sl1 = 16 + sl0;             // rows 16..31 (instr 1)
    const int cl  = l & 3;
    const int cg0 = (cl + (sl0 >> 3)) & 3;
    const int cg1 = (cl + (sl1 >> 3)) & 3;
    const int gof0 = sl0 * 1536 + cg0 * 8;
    const int gof1 = sl1 * 1536 + cg1 * 8;

    u16* myl = lds + w * 4096;

    const int offA0 = quad * 256 + ((((lr >> 3) + 0) - quad) & 3) * 8 + (lr & 7);  // d 0..15
    const int offA1 = quad * 256 + ((((lr >> 3) + 2) - quad) & 3) * 8 + (lr & 7);  // d 16..31

    floatx4 a00 = {0,0,0,0}, a01 = {0,0,0,0}, a10 = {0,0,0,0}, a11 = {0,0,0,0};
    float ks0 = 0.f, ks1 = 0.f;

    {
        const u16* gK = qbase + (size_t)sbase * 1536;
        g2lds16(gK + gof0,       myl);
        g2lds16(gK + gof1,       myl + 512);
        g2lds16(gK + 512 + gof0, myl + 1024);
        g2lds16(gK + 512 + gof1, myl + 1536);
    }
    #pragma unroll
    for (int st = 0; st < 4; st++) {
        if (st < 3) {                      // prefetch next buf before the drain
            const u16* gK = qbase + (size_t)(sbase + (st + 1) * 32) * 1536;
            u16* nl = myl + ((st + 1) & 1) * 2048;
            g2lds16(gK + gof0,       nl);
            g2lds16(gK + gof1,       nl + 512);
            g2lds16(gK + 512 + gof0, nl + 1024);
            g2lds16(gK + 512 + gof1, nl + 1536);
        }
        __syncthreads();                   // vmcnt(0) drain, compiler-safe fence
        const u16* lK = myl + (st & 1) * 2048;
        const u16* lV = lK + 1024;
        union { bf16x8 v; u16 u[8]; } fa0, fa1, fb0, fb1;
        #pragma unroll
        for (int j = 0; j < 8; j++) {
            fa0.u[j] = lK[offA0 + j * 32];
            fa1.u[j] = lK[offA1 + j * 32];
            fb0.u[j] = lV[offA0 + j * 32];
            fb1.u[j] = lV[offA1 + j * 32];
        }
        #pragma unroll
        for (int j = 0; j < 8; j++) { ks0 += bf2f(fa0.u[j]); ks1 += bf2f(fa1.u[j]); }
        a00 = __builtin_amdgcn_mfma_f32_16x16x32_bf16(fa0.v, fb0.v, a00, 0, 0, 0);
        a01 = __builtin_amdgcn_mfma_f32_16x16x32_bf16(fa0.v, fb1.v, a01, 0, 0, 0);
        a10 = __builtin_amdgcn_mfma_f32_16x16x32_bf16(fa1.v, fb0.v, a10, 0, 0, 0);
        a11 = __builtin_amdgcn_mfma_f32_16x16x32_bf16(fa1.v, fb1.v, a11, 0, 0, 0);
    }

    const int p = bh * 32 + chunk * 4 + w;
    float* dst = Pkv + (size_t)p * 1024;
    floatx4 accs[2][2] = {{a00, a01}, {a10, a11}};
    #pragma unroll
    for (int i = 0; i < 2; i++)
        #pragma unroll
        for (int j = 0; j < 2; j++)
            #pragma unroll
            for (int r = 0; r < 4; r++)
                dst[(i * 16 + quad * 4 + r) * 32 + j * 16 + lr] = accs[i][j][r];

    float k0 = ks0 + __shfl_xor(ks0, 16); k0 += __shfl_xor(k0, 32);
    float k1 = ks1 + __shfl_xor(ks1, 16); k1 += __shfl_xor(k1, 32);
    if (quad == 0) {
        PKsum[p * 32 + lr]      = k0;
        PKsum[p * 32 + 16 + lr] = k1;
    }
}

// ---------------- final reduce: KV[bh][1024] = sum of 32 partials; Ksum likewise ----------------
__global__ __launch_bounds__(256) void kv_final(
    const float* __restrict__ Pkv, const float* __restrict__ PKsum,
    float* __restrict__ KV, float* __restrict__ Ksum)
{
    const int bh = blockIdx.x;
    const int t = threadIdx.x;
    float a0 = 0.f, a1 = 0.f, a2 = 0.f, a3 = 0.f;
    for (int p = 0; p < 32; p++) {
        const float* src = Pkv + ((size_t)bh * 32 + p) * 1024;
        a0 += src[t];
        a1 += src[t + 256];
        a2 += src[t + 512];
        a3 += src[t + 768];
    }
    float* dst = KV + (size_t)bh * 1024;
    dst[t] = a0; dst[t + 256] = a1; dst[t + 512] = a2; dst[t + 768] = a3;
    if (t < 32) {
        float s = 0.f;
        for (int p = 0; p < 32; p++) s += PKsum[(bh * 32 + p) * 32 + t];
        Ksum[bh * 32 + t] = s;
    }
}

// ---------------- msg = (Q . KV) * SEQ / (Q . Ksum + eps) ----------------
__global__ __launch_bounds__(256) void msg_kernel(
    const u16* __restrict__ qkv, const float* __restrict__ KV,
    const float* __restrict__ Ksum, u16* __restrict__ msg)
{
    int blk = blockIdx.x;           // 1024 blocks
    int b = blk >> 7;
    int r0 = (blk & 127) * 32;
    int t = threadIdx.x;
    int h = t >> 4;
    int vd = (t & 15) * 2;
    float kv0[32], kv1[32], ksr[32];
    const float* kvh = KV + ((size_t)b * 16 + h) * 1024;
    const float* ksh = Ksum + (b * 16 + h) * 32;
    #pragma unroll
    for (int d = 0; d < 32; d++) {
        kv0[d] = kvh[d * 32 + vd];
        kv1[d] = kvh[d * 32 + vd + 1];
        ksr[d] = ksh[d];
    }
    __shared__ u16 Qs[4 * 512];
    const int srr = t >> 6;
    const int scc = (t & 63) * 8;
    for (int rg = 0; rg < 32; rg += 4) {
        size_t row = (size_t)b * SEQ + r0 + rg;
        uint4 qv = *(const uint4*)(qkv + (row + srr) * 1536 + scc);
        __syncthreads();
        *(uint4*)(Qs + srr * 512 + scc) = qv;
        __syncthreads();
        #pragma unroll
        for (int r2 = 0; r2 < 4; r2++) {
            const u16* qp = Qs + r2 * 512 + h * HD;
            float q[32];
            #pragma unroll
            for (int i0 = 0; i0 < 32; i0 += 8) {
                union { uint4 v; u16 u[8]; } uu;
                uu.v = *(const uint4*)(qp + i0);
                #pragma unroll
                for (int jq = 0; jq < 8; jq++) q[i0 + jq] = bf2f(uu.u[jq]);
            }
            float zdot = 0.f, m0 = 0.f, m1 = 0.f;
            #pragma unroll
            for (int d = 0; d < 32; d++) {
                float qd = q[d];
                zdot += qd * ksr[d];
                m0   += qd * kv0[d];
                m1   += qd * kv1[d];
            }
            float z = (float)SEQ / (zdot + 1e-6f);
            unsigned pack = (unsigned)f2bf(m0 * z) | ((unsigned)f2bf(m1 * z) << 16);
            *(unsigned*)(msg + (row + r2) * C + h * HD + vd) = pack;
        }
    }
}

extern "C" void kernel_launch(void* const* d_in, const int* in_sizes, int n_in,
                              void* d_out, int out_size, void* d_ws, size_t ws_size,
                              hipStream_t stream) {
    const float* x     = (const float*)d_in[0];
    const float* Wq    = (const float*)d_in[1];
    const float* Wk    = (const float*)d_in[2];
    const float* Wv    = (const float*)d_in[3];
    const float* Wm    = (const float*)d_in[4];
    const float* W1    = (const float*)d_in[5];
    const float* b1    = (const float*)d_in[6];
    const float* W2    = (const float*)d_in[7];
    const float* b2    = (const float*)d_in[8];
    const float* g_att = (const float*)d_in[9];
    const float* b_att = (const float*)d_in[10];
    const float* g_ffn = (const float*)d_in[11];
    const float* b_ffn = (const float*)d_in[12];
    float* out = (float*)d_out;

    // Workspace map (live ranges disjoint in time)
    char* ws = (char*)d_ws;
    u16*   Wqkvt = (u16*)(ws);                    // 1.5 MB
    u16*   Wmt   = (u16*)(ws + 0x180000);         // 0.5 MB
    u16*   W1t   = (u16*)(ws + 0x200000);         // 0.5 MB
    u16*   W2t   = (u16*)(ws + 0x280000);         // 0.5 MB
    float* KV    = (float*)(ws + 0x300000);       // 512 KB
    float* Ksum  = (float*)(ws + 0x380000);       // 16 KB
    u16*   hb    = (u16*)(ws + 0x400000);         // 32 MB (LN1 out; reused as msg)
    float* Pkv   = (float*)(ws + 0x400000);       // 16 MB, aliases hb (hb dead in step 4)
    float* PKsum = (float*)(ws + 0x1400000);      // 512 KB
    u16*   qkv   = (u16*)(ws + 0x2400000);        // 96 MB
    u16*   h2    = qkv;                           // 32 MB (qkv dead after step 5)
    u16*   f1    = (u16*)(ws + 0x4400000);        // 32 MB (in qkv tail, dead by step 8)

    // 1. weights -> bf16 transposed
    prep_weights<<<6 * 64, 256, 0, stream>>>(Wq, Wk, Wv, Wm, W1, W2,
                                             Wqkvt, Wmt, W1t, W2t);
    // 2. LN1
    ln_kernel<<<ROWS / 4, 256, 0, stream>>>(x, g_att, b_att, hb);
    // 3. qkv = h @ [Wq|Wk|Wv] with feature-map epilogue  (256^2 8-phase)
    gemm256<0><<<768, 512, 0, stream>>>(hb, Wqkvt, 1536, 6,
                                        qkv, nullptr, nullptr, nullptr);
    // 4. KV/Ksum: MFMA partials + final reduce (no atomics, no memset)
    kv_reduce<<<dim3(128, 8), 256, 0, stream>>>(qkv, Pkv, PKsum);
    kv_final<<<128, 256, 0, stream>>>(Pkv, PKsum, KV, Ksum);
    // 5. msg (overwrites hb region - Pkv already consumed)
    msg_kernel<<<1024, 256, 0, stream>>>(qkv, KV, Ksum, hb);
    // 6. x2 = x + msg @ Wm   (x2 lives in d_out)
    gemm256<1><<<256, 512, 0, stream>>>(hb, Wmt, 512, 2,
                                        nullptr, out, nullptr, x);
    // 7. LN2
    ln_kernel<<<ROWS / 4, 256, 0, stream>>>(out, g_ffn, b_ffn, h2);
    // 8. f1 = gelu(h2 @ W1 + b1)
    gemm256<2><<<256, 512, 0, stream>>>(h2, W1t, 512, 2,
                                        f1, nullptr, b1, nullptr);
    // 9. out = x2 + f1 @ W2 + b2   (in place on d_out)
    gemm256<3><<<256, 512, 0, stream>>>(f1, W2t, 512, 2,
                                        nullptr, out, b2, nullptr);
}